// Round 2
// baseline (1855.195 us; speedup 1.0000x reference)
//
#include <hip/hip_runtime.h>

// out[d] = prod_{e: dst[e]==d} (1 - x[src[e]] * p[e] * w)  + sl * x[d]
// Product -> sum of log2 (messages provably in (0,1]), scatter via fp32 atomicAdd.

#if defined(__has_builtin) && __has_builtin(__builtin_amdgcn_exp2f)
#define EXP2F(v) __builtin_amdgcn_exp2f(v)
#else
#define EXP2F(v) exp2f(v)
#endif

__global__ void init_zero(float* __restrict__ ws, int n) {
    int i = blockIdx.x * blockDim.x + threadIdx.x;
    if (i < n) ws[i] = 0.0f;
}

__global__ __launch_bounds__(256) void edge_scatter(
        const float* __restrict__ x,
        const int* __restrict__ src,
        const int* __restrict__ dst,
        const float* __restrict__ probs,
        const float* __restrict__ w_ptr,
        float* __restrict__ logsum,
        int n_e4) {
    const float w = w_ptr[0];
    int i = blockIdx.x * blockDim.x + threadIdx.x;
    if (i >= n_e4) return;
    int4   s = ((const int4*)src)[i];
    int4   d = ((const int4*)dst)[i];
    float4 p = ((const float4*)probs)[i];
    // gather x (2MB array -> L2/L3 resident)
    float x0 = x[s.x], x1 = x[s.y], x2 = x[s.z], x3 = x[s.w];
    float m0 = __log2f(1.0f - x0 * p.x * w);
    float m1 = __log2f(1.0f - x1 * p.y * w);
    float m2 = __log2f(1.0f - x2 * p.z * w);
    float m3 = __log2f(1.0f - x3 * p.w * w);
    atomicAdd(&logsum[d.x], m0);
    atomicAdd(&logsum[d.y], m1);
    atomicAdd(&logsum[d.z], m2);
    atomicAdd(&logsum[d.w], m3);
}

__global__ void edge_scatter_tail(
        const float* __restrict__ x,
        const int* __restrict__ src,
        const int* __restrict__ dst,
        const float* __restrict__ probs,
        const float* __restrict__ w_ptr,
        float* __restrict__ logsum,
        int start, int n_edges) {
    const float w = w_ptr[0];
    int i = start + blockIdx.x * blockDim.x + threadIdx.x;
    if (i >= n_edges) return;
    float m = __log2f(1.0f - x[src[i]] * probs[i] * w);
    atomicAdd(&logsum[dst[i]], m);
}

__global__ void finalize(const float* __restrict__ x,
                         const float* __restrict__ sl_ptr,
                         const float* __restrict__ logsum,
                         float* __restrict__ out, int n) {
    int i = blockIdx.x * blockDim.x + threadIdx.x;
    if (i < n) out[i] = EXP2F(logsum[i]) + sl_ptr[0] * x[i];
}

extern "C" void kernel_launch(void* const* d_in, const int* in_sizes, int n_in,
                              void* d_out, int out_size, void* d_ws, size_t ws_size,
                              hipStream_t stream) {
    const float* x          = (const float*)d_in[0];   // (N,1) fp32
    const int*   edge_index = (const int*)  d_in[1];   // (2,E) int32
    const float* probs      = (const float*)d_in[2];   // (E,)  fp32
    const float* w          = (const float*)d_in[3];   // (1,)
    const float* sl         = (const float*)d_in[4];   // (1,)

    const int n_nodes = in_sizes[0];
    const int n_edges = in_sizes[1] / 2;
    const int* src = edge_index;
    const int* dst = edge_index + n_edges;
    float* logsum = (float*)d_ws;   // n_nodes fp32, must be zeroed each call

    init_zero<<<(n_nodes + 255) / 256, 256, 0, stream>>>(logsum, n_nodes);

    const int e4 = n_edges / 4;
    if (e4 > 0)
        edge_scatter<<<(e4 + 255) / 256, 256, 0, stream>>>(
            x, src, dst, probs, w, logsum, e4);
    const int tail_start = e4 * 4;
    const int tail = n_edges - tail_start;
    if (tail > 0)
        edge_scatter_tail<<<(tail + 255) / 256, 256, 0, stream>>>(
            x, src, dst, probs, w, logsum, tail_start, n_edges);

    finalize<<<(n_nodes + 255) / 256, 256, 0, stream>>>(
        x, sl, logsum, (float*)d_out, n_nodes);
}

// Round 3
// 1852.010 us; speedup vs baseline: 1.0017x; 1.0017x over previous
//
#include <hip/hip_runtime.h>

// out[d] = prod_{e: dst[e]==d} (1 - x[src[e]] * p[e] * w)  + sl * x[d]
// Product -> sum of log2 (messages provably in (0,1]), scatter via fp32 atomicAdd.
// R3: plain atomicAdd(float*) compiles to a CAS retry loop (safe-for-fine-grained
// semantics) -> 0.6% VALUBusy, 1 GB write traffic. Use hardware fire-and-forget
// global_atomic_add_f32 via unsafeAtomicAdd instead.

#if defined(__has_builtin) && __has_builtin(__builtin_amdgcn_exp2f)
#define EXP2F(v) __builtin_amdgcn_exp2f(v)
#else
#define EXP2F(v) exp2f(v)
#endif

__device__ __forceinline__ void atomic_fadd(float* p, float v) {
    // unsafeAtomicAdd lowers to global_atomic_add_f32 (HW fp32 add in TCC,
    // no CAS loop, no return-value wait) on gfx90a+/gfx94x/gfx950.
    unsafeAtomicAdd(p, v);
}

__global__ void init_zero(float* __restrict__ ws, int n) {
    int i = blockIdx.x * blockDim.x + threadIdx.x;
    if (i < n) ws[i] = 0.0f;
}

__global__ __launch_bounds__(256) void edge_scatter(
        const float* __restrict__ x,
        const int* __restrict__ src,
        const int* __restrict__ dst,
        const float* __restrict__ probs,
        const float* __restrict__ w_ptr,
        float* __restrict__ logsum,
        int n_e4) {
    const float w = w_ptr[0];
    int i = blockIdx.x * blockDim.x + threadIdx.x;
    if (i >= n_e4) return;
    int4   s = ((const int4*)src)[i];
    int4   d = ((const int4*)dst)[i];
    float4 p = ((const float4*)probs)[i];
    // gather x (2MB array -> L2/L3 resident)
    float x0 = x[s.x], x1 = x[s.y], x2 = x[s.z], x3 = x[s.w];
    float m0 = __log2f(1.0f - x0 * p.x * w);
    float m1 = __log2f(1.0f - x1 * p.y * w);
    float m2 = __log2f(1.0f - x2 * p.z * w);
    float m3 = __log2f(1.0f - x3 * p.w * w);
    atomic_fadd(&logsum[d.x], m0);
    atomic_fadd(&logsum[d.y], m1);
    atomic_fadd(&logsum[d.z], m2);
    atomic_fadd(&logsum[d.w], m3);
}

__global__ void edge_scatter_tail(
        const float* __restrict__ x,
        const int* __restrict__ src,
        const int* __restrict__ dst,
        const float* __restrict__ probs,
        const float* __restrict__ w_ptr,
        float* __restrict__ logsum,
        int start, int n_edges) {
    const float w = w_ptr[0];
    int i = start + blockIdx.x * blockDim.x + threadIdx.x;
    if (i >= n_edges) return;
    float m = __log2f(1.0f - x[src[i]] * probs[i] * w);
    atomic_fadd(&logsum[dst[i]], m);
}

__global__ void finalize(const float* __restrict__ x,
                         const float* __restrict__ sl_ptr,
                         const float* __restrict__ logsum,
                         float* __restrict__ out, int n) {
    int i = blockIdx.x * blockDim.x + threadIdx.x;
    if (i < n) out[i] = EXP2F(logsum[i]) + sl_ptr[0] * x[i];
}

extern "C" void kernel_launch(void* const* d_in, const int* in_sizes, int n_in,
                              void* d_out, int out_size, void* d_ws, size_t ws_size,
                              hipStream_t stream) {
    const float* x          = (const float*)d_in[0];   // (N,1) fp32
    const int*   edge_index = (const int*)  d_in[1];   // (2,E) int32
    const float* probs      = (const float*)d_in[2];   // (E,)  fp32
    const float* w          = (const float*)d_in[3];   // (1,)
    const float* sl         = (const float*)d_in[4];   // (1,)

    const int n_nodes = in_sizes[0];
    const int n_edges = in_sizes[1] / 2;
    const int* src = edge_index;
    const int* dst = edge_index + n_edges;
    float* logsum = (float*)d_ws;   // n_nodes fp32, must be zeroed each call

    init_zero<<<(n_nodes + 255) / 256, 256, 0, stream>>>(logsum, n_nodes);

    const int e4 = n_edges / 4;
    if (e4 > 0)
        edge_scatter<<<(e4 + 255) / 256, 256, 0, stream>>>(
            x, src, dst, probs, w, logsum, e4);
    const int tail_start = e4 * 4;
    const int tail = n_edges - tail_start;
    if (tail > 0)
        edge_scatter_tail<<<(tail + 255) / 256, 256, 0, stream>>>(
            x, src, dst, probs, w, logsum, tail_start, n_edges);

    finalize<<<(n_nodes + 255) / 256, 256, 0, stream>>>(
        x, sl, logsum, (float*)d_out, n_nodes);
}

// Round 4
// 1846.646 us; speedup vs baseline: 1.0046x; 1.0029x over previous
//
#include <hip/hip_runtime.h>

// out[d] = prod_{e: dst[e]==d} (1 - x[src[e]] * p[e] * w)  + sl * x[d]
// Product -> sum of log2 (messages in (0,1]), scatter-add of logs.
//
// R4: agent-scope fp32 atomics RMW at the memory side (WRITE_SIZE was exactly
// 32M x 32B = 1 GB of random HBM sectors -> 1550 us). Fix: 8 per-XCD replicas
// of logsum; each wave atomics into replica[HW_REG_XCC_ID] using a raw
// global_atomic_add_f32 with no sc bits -> RMW executes in the XCD-local L2
// (2 MB replica is L2-resident). Same-address atomics all originate on one
// XCD => coherent by construction. End-of-kernel release flushes L2 so the
// finalize kernel sees the sums.

#if defined(__has_builtin) && __has_builtin(__builtin_amdgcn_exp2f)
#define EXP2F(v) __builtin_amdgcn_exp2f(v)
#else
#define EXP2F(v) exp2f(v)
#endif

// hwreg(HW_REG_XCC_ID=20, offset=0, size=32) -> imm = (31<<11)|20
__device__ __forceinline__ unsigned xcc_id() {
    return __builtin_amdgcn_s_getreg((31 << 11) | 20) & 7u;
}

// Fire-and-forget fp32 atomic add with NO sc0/sc1 bits: executes in the
// local XCD's TCC (L2), line stays cached. NOT device-coherent -- only
// valid because all atomics to a given replica come from that one XCD.
__device__ __forceinline__ void atomic_fadd_l2(float* p, float v) {
    asm volatile("global_atomic_add_f32 %0, %1, off" :: "v"(p), "v"(v) : "memory");
}

__device__ __forceinline__ void atomic_fadd_agent(float* p, float v) {
    unsafeAtomicAdd(p, v);  // agent scope, memory-side RMW (slow but always safe)
}

__global__ void init_zero(float* __restrict__ ws, int n) {
    int i = blockIdx.x * blockDim.x + threadIdx.x;
    if (i < n) ws[i] = 0.0f;
}

template <bool USE_L2>
__global__ __launch_bounds__(256) void edge_scatter(
        const float* __restrict__ x,
        const int* __restrict__ src,
        const int* __restrict__ dst,
        const float* __restrict__ probs,
        const float* __restrict__ w_ptr,
        float* __restrict__ logsum,   // USE_L2: 8 replicas of n_nodes
        int n_nodes, int n_e4) {
    const float w = w_ptr[0];
    float* ls = USE_L2 ? (logsum + (size_t)xcc_id() * (size_t)n_nodes) : logsum;
    int i = blockIdx.x * blockDim.x + threadIdx.x;
    if (i >= n_e4) return;
    int4   s = ((const int4*)src)[i];
    int4   d = ((const int4*)dst)[i];
    float4 p = ((const float4*)probs)[i];
    float x0 = x[s.x], x1 = x[s.y], x2 = x[s.z], x3 = x[s.w];
    float m0 = __log2f(1.0f - x0 * p.x * w);
    float m1 = __log2f(1.0f - x1 * p.y * w);
    float m2 = __log2f(1.0f - x2 * p.z * w);
    float m3 = __log2f(1.0f - x3 * p.w * w);
    if (USE_L2) {
        atomic_fadd_l2(&ls[d.x], m0);
        atomic_fadd_l2(&ls[d.y], m1);
        atomic_fadd_l2(&ls[d.z], m2);
        atomic_fadd_l2(&ls[d.w], m3);
    } else {
        atomic_fadd_agent(&ls[d.x], m0);
        atomic_fadd_agent(&ls[d.y], m1);
        atomic_fadd_agent(&ls[d.z], m2);
        atomic_fadd_agent(&ls[d.w], m3);
    }
}

template <bool USE_L2>
__global__ void edge_scatter_tail(
        const float* __restrict__ x,
        const int* __restrict__ src,
        const int* __restrict__ dst,
        const float* __restrict__ probs,
        const float* __restrict__ w_ptr,
        float* __restrict__ logsum,
        int n_nodes, int start, int n_edges) {
    const float w = w_ptr[0];
    float* ls = USE_L2 ? (logsum + (size_t)xcc_id() * (size_t)n_nodes) : logsum;
    int i = start + blockIdx.x * blockDim.x + threadIdx.x;
    if (i >= n_edges) return;
    float m = __log2f(1.0f - x[src[i]] * probs[i] * w);
    if (USE_L2) atomic_fadd_l2(&ls[dst[i]], m);
    else        atomic_fadd_agent(&ls[dst[i]], m);
}

__global__ void finalize8(const float* __restrict__ x,
                          const float* __restrict__ sl_ptr,
                          const float* __restrict__ logsum,  // 8 x n
                          float* __restrict__ out, int n) {
    int i = blockIdx.x * blockDim.x + threadIdx.x;
    if (i >= n) return;
    float s = 0.0f;
    #pragma unroll
    for (int r = 0; r < 8; ++r) s += logsum[(size_t)r * n + i];
    out[i] = EXP2F(s) + sl_ptr[0] * x[i];
}

__global__ void finalize1(const float* __restrict__ x,
                          const float* __restrict__ sl_ptr,
                          const float* __restrict__ logsum,
                          float* __restrict__ out, int n) {
    int i = blockIdx.x * blockDim.x + threadIdx.x;
    if (i < n) out[i] = EXP2F(logsum[i]) + sl_ptr[0] * x[i];
}

extern "C" void kernel_launch(void* const* d_in, const int* in_sizes, int n_in,
                              void* d_out, int out_size, void* d_ws, size_t ws_size,
                              hipStream_t stream) {
    const float* x          = (const float*)d_in[0];   // (N,1) fp32
    const int*   edge_index = (const int*)  d_in[1];   // (2,E) int32
    const float* probs      = (const float*)d_in[2];   // (E,)  fp32
    const float* w          = (const float*)d_in[3];   // (1,)
    const float* sl         = (const float*)d_in[4];   // (1,)

    const int n_nodes = in_sizes[0];
    const int n_edges = in_sizes[1] / 2;
    const int* src = edge_index;
    const int* dst = edge_index + n_edges;
    float* logsum = (float*)d_ws;

    const bool use_l2 = ws_size >= (size_t)8 * (size_t)n_nodes * sizeof(float);
    const int n_ls = use_l2 ? 8 * n_nodes : n_nodes;

    init_zero<<<(n_ls + 255) / 256, 256, 0, stream>>>(logsum, n_ls);

    const int e4 = n_edges / 4;
    const int tail_start = e4 * 4;
    const int tail = n_edges - tail_start;

    if (use_l2) {
        if (e4 > 0)
            edge_scatter<true><<<(e4 + 255) / 256, 256, 0, stream>>>(
                x, src, dst, probs, w, logsum, n_nodes, e4);
        if (tail > 0)
            edge_scatter_tail<true><<<(tail + 255) / 256, 256, 0, stream>>>(
                x, src, dst, probs, w, logsum, n_nodes, tail_start, n_edges);
        finalize8<<<(n_nodes + 255) / 256, 256, 0, stream>>>(
            x, sl, logsum, (float*)d_out, n_nodes);
    } else {
        if (e4 > 0)
            edge_scatter<false><<<(e4 + 255) / 256, 256, 0, stream>>>(
                x, src, dst, probs, w, logsum, n_nodes, e4);
        if (tail > 0)
            edge_scatter_tail<false><<<(tail + 255) / 256, 256, 0, stream>>>(
                x, src, dst, probs, w, logsum, n_nodes, tail_start, n_edges);
        finalize1<<<(n_nodes + 255) / 256, 256, 0, stream>>>(
            x, sl, logsum, (float*)d_out, n_nodes);
    }
}